// Round 15
// baseline (614.064 us; speedup 1.0000x reference)
//
#include <hip/hip_runtime.h>
#include <hip/hip_bf16.h>

#define T_TOKENS 8192
#define D_DIM 1024
#define H_DIM 4096
#define E_NUM 8
#define CAP 8192
#define CNT_PAD 16

#define TPB_G 32
#define GATE_BLKS (T_TOKENS / TPB_G)
#define TRW1_BLKS ((D_DIM / 64) * (H_DIM / 64) * E_NUM)
#define TRW2_BLKS ((H_DIM / 64) * (D_DIM / 64) * E_NUM)

typedef short bf16x8 __attribute__((ext_vector_type(8)));
typedef float f32x4 __attribute__((ext_vector_type(4)));
typedef unsigned short u16x8 __attribute__((ext_vector_type(8)));

__device__ inline unsigned short f2bf(float f) {
    __hip_bfloat16 h = __float2bfloat16(f);
    return *reinterpret_cast<unsigned short*>(&h);
}

__device__ inline float gelu_sig(float v) {
    float x = v * (1.5957691216057308f + 0.07135481627f * v * v);
    return v * __builtin_amdgcn_rcpf(1.0f + __expf(-x));
}

__device__ inline void gld_lds16(const unsigned short* g, unsigned short* lds) {
    __builtin_amdgcn_global_load_lds(
        (const __attribute__((address_space(1))) void*)g,
        (__attribute__((address_space(3))) void*)lds, 16, 0, 0);
}

#define WAITV(N) do { asm volatile("s_waitcnt vmcnt(" #N ")" ::: "memory"); \
                      __builtin_amdgcn_sched_barrier(0); } while (0)
#define LGKM0    do { asm volatile("s_waitcnt lgkmcnt(0)" ::: "memory"); \
                      __builtin_amdgcn_sched_barrier(0); } while (0)
#define SBAR     do { __builtin_amdgcn_sched_barrier(0); \
                      __builtin_amdgcn_s_barrier(); \
                      __builtin_amdgcn_sched_barrier(0); } while (0)

#define XCD_ITEMS(T)                                                          \
    int xcd = blockIdx.x & 7;                                                 \
    int lb  = blockIdx.x >> 3;                                                \
    int nbx = gridDim.x >> 3;                                                 \
    int q_ = (T) >> 3, r_ = (T) & 7;                                          \
    int base_ = (xcd < r_) ? xcd * (q_ + 1) : r_ * (q_ + 1) + (xcd - r_) * q_;\
    int cntx_ = (xcd < r_) ? q_ + 1 : q_;

// ---------------- fused prepass: gate(+x cvt) | trw(w1) | trw(w2) ----------
__device__ inline void trw_body(const float* __restrict__ w,
                                unsigned short* __restrict__ wt,
                                int K, int N, int bb,
                                unsigned short (*tb)[72]) {
    int nk = K / 64, nn = N / 64;
    int e = bb / (nk * nn);
    int rem = bb - e * (nk * nn);
    int k0 = (rem % nk) * 64;
    int n0 = (rem / nk) * 64;
    const float* we = w + (size_t)e * K * N + (size_t)k0 * N + n0;
    unsigned short* wte = wt + (size_t)e * K * N + (size_t)n0 * K + k0;
    int tid = threadIdx.x;

    int kg = tid >> 4;
    int nq = (tid & 15) * 4;
    float4 r0 = *(const float4*)(we + (size_t)(kg * 4 + 0) * N + nq);
    float4 r1 = *(const float4*)(we + (size_t)(kg * 4 + 1) * N + nq);
    float4 r2 = *(const float4*)(we + (size_t)(kg * 4 + 2) * N + nq);
    float4 r3 = *(const float4*)(we + (size_t)(kg * 4 + 3) * N + nq);
    ushort4 u;
    u.x = f2bf(r0.x); u.y = f2bf(r1.x); u.z = f2bf(r2.x); u.w = f2bf(r3.x);
    *(ushort4*)&tb[nq + 0][kg * 4] = u;
    u.x = f2bf(r0.y); u.y = f2bf(r1.y); u.z = f2bf(r2.y); u.w = f2bf(r3.y);
    *(ushort4*)&tb[nq + 1][kg * 4] = u;
    u.x = f2bf(r0.z); u.y = f2bf(r1.z); u.z = f2bf(r2.z); u.w = f2bf(r3.z);
    *(ushort4*)&tb[nq + 2][kg * 4] = u;
    u.x = f2bf(r0.w); u.y = f2bf(r1.w); u.z = f2bf(r2.w); u.w = f2bf(r3.w);
    *(ushort4*)&tb[nq + 3][kg * 4] = u;

    __syncthreads();

#pragma unroll
    for (int p = 0; p < 2; ++p) {
        int n = p * 32 + (tid >> 3);
        int kc = (tid & 7) * 8;
        u16x8 v = *(const u16x8*)&tb[n][kc];
        *(u16x8*)(wte + (size_t)n * K + kc) = v;
    }
}

__global__ __launch_bounds__(256) void prep_kernel(const float* __restrict__ x,
                                                   const float* __restrict__ gw,
                                                   const float* __restrict__ w1,
                                                   const float* __restrict__ w2,
                                                   int* __restrict__ cnt,
                                                   int* __restrict__ tok,
                                                   float* __restrict__ cf,
                                                   unsigned short* __restrict__ xb,
                                                   unsigned short* __restrict__ w1t,
                                                   unsigned short* __restrict__ w2t) {
    __shared__ __align__(16) unsigned short tb[64][72];
    __shared__ int ls0[TPB_G], ls1[TPB_G];
    __shared__ float lp0[TPB_G], lp1[TPB_G];
    int b = blockIdx.x;
    if (b >= GATE_BLKS) {
        int bb = b - GATE_BLKS;
        if (bb < TRW1_BLKS) trw_body(w1, w1t, D_DIM, H_DIM, bb, tb);
        else                trw_body(w2, w2t, H_DIM, D_DIM, bb - TRW1_BLKS, tb);
        return;
    }
    int tid = threadIdx.x;
    int lane = tid & 63, wv = tid >> 6;
#pragma unroll
    for (int rep = 0; rep < TPB_G / 4; ++rep) {
        int ti = rep * 4 + wv;
        int t = b * TPB_G + ti;
        const float* xr = x + (size_t)t * D_DIM;
        unsigned short* xbr = xb + (size_t)t * D_DIM;
        double acc[E_NUM];
#pragma unroll
        for (int e = 0; e < E_NUM; ++e) acc[e] = 0.0;
#pragma unroll
        for (int it = 0; it < 4; ++it) {
            int d = it * 256 + lane * 4;
            float4 v = *(const float4*)(xr + d);
            ushort4 u;
            u.x = f2bf(v.x); u.y = f2bf(v.y); u.z = f2bf(v.z); u.w = f2bf(v.w);
            *(ushort4*)(xbr + d) = u;
            const float vv[4] = {v.x, v.y, v.z, v.w};
#pragma unroll
            for (int j = 0; j < 4; ++j) {
                const float* g = gw + (size_t)(d + j) * E_NUM;
#pragma unroll
                for (int e = 0; e < E_NUM; ++e) acc[e] += (double)vv[j] * (double)g[e];
            }
        }
#pragma unroll
        for (int e = 0; e < E_NUM; ++e) {
            double v = acc[e];
#pragma unroll
            for (int off = 32; off >= 1; off >>= 1) v += __shfl_xor(v, off);
            acc[e] = v;
        }
        if (lane == 0) {
            int s0 = 0;
#pragma unroll
            for (int e = 1; e < E_NUM; ++e) if (acc[e] > acc[s0]) s0 = e;
            int s1 = -1;
#pragma unroll
            for (int e = 0; e < E_NUM; ++e) if (e != s0 && (s1 < 0 || acc[e] > acc[s1])) s1 = e;
            float l0 = (float)acc[s0], l1 = (float)acc[s1];
            float p1 = __expf(l1 - l0);
            float inv = 1.0f / (1.0f + p1);
            ls0[ti] = s0; ls1[ti] = s1;
            lp0[ti] = inv; lp1[ti] = p1 * inv;
        }
    }
    __syncthreads();
    if (tid < E_NUM) {
        int e = tid, c = 0;
#pragma unroll
        for (int i = 0; i < TPB_G; ++i) c += (ls0[i] == e) + (ls1[i] == e);
        if (c > 0) {
            int q = atomicAdd(&cnt[e * CNT_PAD], c);
            for (int i = 0; i < TPB_G; ++i) {
                int t = b * TPB_G + i;
                if (ls0[i] == e) { tok[e * CAP + q] = t; cf[e * CAP + q] = lp0[i]; ++q; }
                if (ls1[i] == e) { tok[e * CAP + q] = t; cf[e * CAP + q] = lp1[i]; ++q; }
            }
        }
    }
}

// ===== GEMMs: 256x256 tile, 8 waves, BK=32, ring-3 slots, counted vmcnt ====
// LDS row = 32 bf16 = 4 chunks of 16B; LDS[r][c] holds global chunk c^(r&3).
// Stage K(t+2) into slot (t+2)%3 during K-tile t; WAITV(4)+SBAR once per
// K-tile guarantees slot t landed for all waves; single barrier per K-tile
// (ring-3 WAR audit in round notes). Flight ~= 2 K-tiles, never drained.

__global__ __launch_bounds__(512, 2) void gemm1_fast(const unsigned short* __restrict__ xb,
                                                     const unsigned short* __restrict__ w1t,
                                                     const float* __restrict__ b1,
                                                     const int* __restrict__ cnt,
                                                     const int* __restrict__ tok,
                                                     unsigned short* __restrict__ Hbuf) {
    __shared__ __align__(16) unsigned short As[3][256][32];
    __shared__ __align__(16) unsigned short Bs[3][256][32];
    __shared__ int s_tok[256];

    int tid = threadIdx.x, lane = tid & 63, wv = tid >> 6;
    int wm = wv >> 2, wn = wv & 3;              // 2x4 wave grid, 128x64/wave
    int lm = lane & 15, lkq = lane >> 4;        // frag col / k-quarter
    int srow = tid >> 2;                        // staging row 0..127
    int schunk = (((tid & 3) ^ (srow & 3)) << 3);
    int rdc = ((lkq ^ (lm & 3)) << 3);          // read-side swizzled chunk

    int ne_[E_NUM], offs_[E_NUM], pref[E_NUM + 1];
    pref[0] = 0;
    int off = 0;
#pragma unroll
    for (int e = 0; e < E_NUM; ++e) {
        ne_[e] = cnt[e * CNT_PAD];
        offs_[e] = off; off += ne_[e];
        pref[e + 1] = pref[e] + ((ne_[e] + 255) >> 8) * 16;   // nbm(256) * 16 n
    }
    int T = pref[E_NUM];

    XCD_ITEMS(T)
    for (int ii = lb; ii < cntx_; ii += nbx) {
        int w = base_ + ii;
        int e = 0;
#pragma unroll
        for (int q = 0; q < E_NUM - 1; ++q) e += (w >= pref[q + 1]) ? 1 : 0;
        int local = w - pref[e];
        int bm0 = (local >> 4) * 256;
        int n0 = (local & 15) * 256;
        int ne = ne_[e];
        int offs = offs_[e];
        const unsigned short* w1e = w1t + (size_t)e * H_DIM * D_DIM;

        __syncthreads();    // prev item done (drains vmem too)
        if (tid < 256) s_tok[tid] = tok[e * CAP + min(bm0 + tid, ne - 1)];
        __syncthreads();

        const unsigned short* gA[2];
        const unsigned short* gB[2];
#pragma unroll
        for (int u = 0; u < 2; ++u) {
            gA[u] = xb + (size_t)s_tok[u * 128 + srow] * D_DIM + schunk;
            gB[u] = w1e + (size_t)(n0 + u * 128 + srow) * D_DIM + schunk;
        }
        float bias_v[4];
#pragma unroll
        for (int j = 0; j < 4; ++j)
            bias_v[j] = b1[(size_t)e * H_DIM + n0 + wn * 64 + j * 16 + lm];

        f32x4 acc[8][4];
#pragma unroll
        for (int i = 0; i < 8; ++i)
#pragma unroll
            for (int j = 0; j < 4; ++j) { f32x4 z = {0.f, 0.f, 0.f, 0.f}; acc[i][j] = z; }

        auto STAGE_A = [&](int sl, int kb, int u) {
            gld_lds16(gA[u] + kb * 32, &As[sl][u * 128 + wv * 16][0]);
        };
        auto STAGE_B = [&](int sl, int kb, int u) {
            gld_lds16(gB[u] + kb * 32, &Bs[sl][u * 128 + wv * 16][0]);
        };

        const int NT = D_DIM / 32;   // 32
        STAGE_A(0, 0, 0); STAGE_A(0, 0, 1); STAGE_B(0, 0, 0); STAGE_B(0, 0, 1);
        STAGE_A(1, 1, 0); STAGE_A(1, 1, 1); STAGE_B(1, 1, 0); STAGE_B(1, 1, 1);

        int s = 0, s2 = 2;
        for (int t = 0; t < NT; ++t) {
            if (t + 1 < NT) { WAITV(4); } else { WAITV(0); }
            SBAR;                                   // slot s landed for ALL waves
            bf16x8 bfr[4], afr[4];
#pragma unroll
            for (int f = 0; f < 4; ++f)
                bfr[f] = *(const bf16x8*)&Bs[s][wn * 64 + f * 16 + lm][rdc];
#pragma unroll
            for (int f = 0; f < 4; ++f)
                afr[f] = *(const bf16x8*)&As[s][wm * 128 + f * 16 + lm][rdc];
            if (t + 2 < NT) { STAGE_A(s2, t + 2, 0); STAGE_A(s2, t + 2, 1); }
            LGKM0;
            __builtin_amdgcn_s_setprio(1);
#pragma unroll
            for (int i = 0; i < 4; ++i)
#pragma unroll
                for (int j = 0; j < 4; ++j)
                    acc[i][j] = __builtin_amdgcn_mfma_f32_16x16x32_bf16(afr[i], bfr[j], acc[i][j], 0, 0, 0);
            __builtin_amdgcn_s_setprio(0);
            // phase B: rows 128..255 of wave tile
#pragma unroll
            for (int f = 0; f < 4; ++f)
                afr[f] = *(const bf16x8*)&As[s][wm * 128 + 64 + f * 16 + lm][rdc];
            if (t + 2 < NT) { STAGE_B(s2, t + 2, 0); STAGE_B(s2, t + 2, 1); }
            LGKM0;
            __builtin_amdgcn_s_setprio(1);
#pragma unroll
            for (int i = 0; i < 4; ++i)
#pragma unroll
                for (int j = 0; j < 4; ++j)
                    acc[4 + i][j] = __builtin_amdgcn_mfma_f32_16x16x32_bf16(afr[i], bfr[j], acc[4 + i][j], 0, 0, 0);
            __builtin_amdgcn_s_setprio(0);
            s = (s == 2) ? 0 : s + 1;
            s2 = (s2 == 2) ? 0 : s2 + 1;
        }

#pragma unroll
        for (int i = 0; i < 8; ++i) {
            int frow = wm * 128 + ((i < 4) ? i * 16 : 64 + (i - 4) * 16);
#pragma unroll
            for (int r = 0; r < 4; ++r) {
                int row = frow + lkq * 4 + r;
                int gr = bm0 + row;
                if (gr >= ne) continue;
                size_t rb = (size_t)(offs + gr) * H_DIM;
#pragma unroll
                for (int j = 0; j < 4; ++j) {
                    int gn = n0 + wn * 64 + j * 16 + lm;
                    float v = acc[i][j][r] + bias_v[j];
                    Hbuf[rb + gn] = f2bf(gelu_sig(v));
                }
            }
        }
    }
}

__global__ __launch_bounds__(512, 2) void gemm2_fast(const unsigned short* __restrict__ Hbuf,
                                                     const unsigned short* __restrict__ w2t,
                                                     const float* __restrict__ b2,
                                                     const int* __restrict__ cnt,
                                                     const int* __restrict__ tok,
                                                     const float* __restrict__ cf,
                                                     float* __restrict__ out) {
    __shared__ __align__(16) unsigned short As[3][256][32];
    __shared__ __align__(16) unsigned short Bs[3][256][32];
    __shared__ int s_tok[256];
    __shared__ float s_cf[256];

    int tid = threadIdx.x, lane = tid & 63, wv = tid >> 6;
    int wm = wv >> 2, wn = wv & 3;
    int lm = lane & 15, lkq = lane >> 4;
    int srow = tid >> 2;
    int schunk = (((tid & 3) ^ (srow & 3)) << 3);
    int rdc = ((lkq ^ (lm & 3)) << 3);

    int ne_[E_NUM], offs_[E_NUM], pref[E_NUM + 1];
    pref[0] = 0;
    int off = 0;
#pragma unroll
    for (int e = 0; e < E_NUM; ++e) {
        ne_[e] = cnt[e * CNT_PAD];
        offs_[e] = off; off += ne_[e];
        pref[e + 1] = pref[e] + ((ne_[e] + 255) >> 8) * 4;    // nbm(256) * 4 n
    }
    int T = pref[E_NUM];

    XCD_ITEMS(T)
    for (int ii = lb; ii < cntx_; ii += nbx) {
        int w = base_ + ii;
        int e = 0;
#pragma unroll
        for (int q = 0; q < E_NUM - 1; ++q) e += (w >= pref[q + 1]) ? 1 : 0;
        int local = w - pref[e];
        int bm0 = (local >> 2) * 256;
        int n0 = (local & 3) * 256;
        int ne = ne_[e];
        int offs = offs_[e];
        const unsigned short* w2e = w2t + (size_t)e * H_DIM * D_DIM;

        __syncthreads();
        if (tid < 256) {
            int gi = min(bm0 + tid, ne - 1);
            s_tok[tid] = tok[e * CAP + gi];
            s_cf[tid] = cf[e * CAP + gi];
        }
        __syncthreads();

        const unsigned short* gA[2];
        const unsigned short* gB[2];
#pragma unroll
        for (int u = 0; u < 2; ++u) {
            gA[u] = Hbuf + (size_t)(offs + min(bm0 + u * 128 + srow, ne - 1)) * H_DIM + schunk;
            gB[u] = w2e + (size_t)(n0 + u * 128 + srow) * H_DIM + schunk;
        }
        float bias_v[4];
#pragma unroll
        for (int j = 0; j < 4; ++j)
            bias_v[j] = b2[(size_t)e * D_DIM + n0 + wn * 64 + j * 16 + lm];

        f32x4 acc[8][4];
#pragma unroll
        for (int i = 0; i < 8; ++i)
#pragma unroll
            for (int j = 0; j < 4; ++j) { f32x4 z = {0.f, 0.f, 0.f, 0.f}; acc[i][j] = z; }

        auto STAGE_A = [&](int sl, int kb, int u) {
            gld_lds16(gA[u] + kb * 32, &As[sl][u * 128 + wv * 16][0]);
        };
        auto STAGE_B = [&](int sl, int kb, int u) {
            gld_lds16(gB[u] + kb * 32, &Bs[sl][u * 128 + wv * 16][0]);
        };

        const int NT = H_DIM / 32;   // 128
        STAGE_A(0, 0, 0); STAGE_A(0, 0, 1); STAGE_B(0, 0, 0); STAGE_B(0, 0, 1);
        STAGE_A(1, 1, 0); STAGE_A(1, 1, 1); STAGE_B(1, 1, 0); STAGE_B(1, 1, 1);

        int s = 0, s2 = 2;
        for (int t = 0; t < NT; ++t) {
            if (t + 1 < NT) { WAITV(4); } else { WAITV(0); }
            SBAR;
            bf16x8 bfr[4], afr[4];
#pragma unroll
            for (int f = 0; f < 4; ++f)
                bfr[f] = *(const bf16x8*)&Bs[s][wn * 64 + f * 16 + lm][rdc];
#pragma unroll
            for (int f = 0; f < 4; ++f)
                afr[f] = *(const bf16x8*)&As[s][wm * 128 + f * 16 + lm][rdc];
            if (t + 2 < NT) { STAGE_A(s2, t + 2, 0); STAGE_A(s2, t + 2, 1); }
            LGKM0;
            __builtin_amdgcn_s_setprio(1);
#pragma unroll
            for (int i = 0; i < 4; ++i)
#pragma unroll
                for (int j = 0; j < 4; ++j)
                    acc[i][j] = __builtin_amdgcn_mfma_f32_16x16x32_bf16(afr[i], bfr[j], acc[i][j], 0, 0, 0);
            __builtin_amdgcn_s_setprio(0);
#pragma unroll
            for (int f = 0; f < 4; ++f)
                afr[f] = *(const bf16x8*)&As[s][wm * 128 + 64 + f * 16 + lm][rdc];
            if (t + 2 < NT) { STAGE_B(s2, t + 2, 0); STAGE_B(s2, t + 2, 1); }
            LGKM0;
            __builtin_amdgcn_s_setprio(1);
#pragma unroll
            for (int i = 0; i < 4; ++i)
#pragma unroll
                for (int j = 0; j < 4; ++j)
                    acc[4 + i][j] = __builtin_amdgcn_mfma_f32_16x16x32_bf16(afr[i], bfr[j], acc[4 + i][j], 0, 0, 0);
            __builtin_amdgcn_s_setprio(0);
            s = (s == 2) ? 0 : s + 1;
            s2 = (s2 == 2) ? 0 : s2 + 1;
        }

#pragma unroll
        for (int i = 0; i < 8; ++i) {
            int frow = wm * 128 + ((i < 4) ? i * 16 : 64 + (i - 4) * 16);
#pragma unroll
            for (int r = 0; r < 4; ++r) {
                int row = frow + lkq * 4 + r;
                int gr = bm0 + row;
                if (gr >= ne) continue;
                int tk = s_tok[row];
                float cw = s_cf[row];
#pragma unroll
                for (int j = 0; j < 4; ++j) {
                    int gn = n0 + wn * 64 + j * 16 + lm;
                    float y = acc[i][j][r] + bias_v[j];
                    atomicAdd(&out[(size_t)tk * D_DIM + gn], cw * y);
                }
            }
        }
    }
}

extern "C" void kernel_launch(void* const* d_in, const int* in_sizes, int n_in,
                              void* d_out, int out_size, void* d_ws, size_t ws_size,
                              hipStream_t stream) {
    const float* x  = (const float*)d_in[0];
    const float* gw = (const float*)d_in[1];
    const float* w1 = (const float*)d_in[2];
    const float* b1 = (const float*)d_in[3];
    const float* w2 = (const float*)d_in[4];
    const float* b2 = (const float*)d_in[5];
    float* out = (float*)d_out;

    char* ws = (char*)d_ws;
    const size_t SZ_CNT   = E_NUM * CNT_PAD * 4;
    const size_t SZ_ROUTE = SZ_CNT + (size_t)2 * E_NUM * CAP * 4;
    const size_t SZ_XB    = (size_t)T_TOKENS * D_DIM * 2;
    const size_t SZ_W     = (size_t)E_NUM * D_DIM * H_DIM * 2;
    const size_t SZ_H     = (size_t)2 * T_TOKENS * H_DIM * 2;

    int*   cnt = (int*)ws;
    int*   tok = (int*)(ws + SZ_CNT);
    float* cff = (float*)(ws + SZ_CNT + E_NUM * CAP * 4);

    size_t need_fast = SZ_ROUTE + SZ_XB + 2 * SZ_W + SZ_H;
    if (ws_size < need_fast) return;  // loud failure: out stays poisoned

    unsigned short* xb   = (unsigned short*)(ws + SZ_ROUTE);
    unsigned short* w1t  = (unsigned short*)(ws + SZ_ROUTE + SZ_XB);
    unsigned short* w2t  = (unsigned short*)(ws + SZ_ROUTE + SZ_XB + SZ_W);
    unsigned short* Hbuf = (unsigned short*)(ws + SZ_ROUTE + SZ_XB + 2 * SZ_W);

    hipMemsetAsync(cnt, 0, SZ_CNT, stream);
    hipMemsetAsync(out, 0, (size_t)out_size * sizeof(float), stream);

    prep_kernel<<<GATE_BLKS + TRW1_BLKS + TRW2_BLKS, 256, 0, stream>>>(
        x, gw, w1, w2, cnt, tok, cff, xb, w1t, w2t);

    gemm1_fast<<<256, 512, 0, stream>>>(xb, w1t, b1, cnt, tok, Hbuf);
    gemm2_fast<<<256, 512, 0, stream>>>(Hbuf, w2t, b2, cnt, tok, cff, out);
}